// Round 1
// baseline (608.963 us; speedup 1.0000x reference)
//
#include <hip/hip_runtime.h>
#include <cstdint>
#include <cstddef>

#define NN 32
#define NODE_ELEMS 1605632  // 8*56*56*64 elements per slot (NHWC); bf16 storage

typedef unsigned __int128 u128;
typedef __attribute__((ext_vector_type(8))) short bf16x8;
typedef __attribute__((ext_vector_type(4))) float f32x4;

// ---------------- host: replicate np.random.default_rng(0).random((32,32)) < 0.25 ----
static void compute_adj(bool adj[NN][NN]) {
  uint32_t pool[4];
  uint32_t hc = 0x43b0d7e5u;
  auto hashmix = [&hc](uint32_t v) -> uint32_t {
    v ^= hc; hc *= 0x931e8875u; v *= hc; v ^= v >> 16; return v;
  };
  auto mix = [](uint32_t x, uint32_t y) -> uint32_t {
    uint32_t r = x * 0xca01f9ddu - y * 0x4973f715u; r ^= r >> 16; return r;
  };
  for (int i = 0; i < 4; i++) pool[i] = hashmix(0u);
  for (int s = 0; s < 4; s++)
    for (int d = 0; d < 4; d++)
      if (s != d) pool[d] = mix(pool[d], hashmix(pool[s]));
  uint32_t hb = 0x8b51f9ddu;
  uint32_t w[8];
  for (int k = 0; k < 8; k++) {
    uint32_t v = pool[k & 3];
    v ^= hb; hb *= 0x58f38dedu; v *= hb; v ^= v >> 16;
    w[k] = v;
  }
  uint64_t s64[4];
  for (int j = 0; j < 4; j++) s64[j] = (uint64_t)w[2 * j] | ((uint64_t)w[2 * j + 1] << 32);
  u128 initstate = ((u128)s64[0] << 64) | s64[1];
  u128 initseq   = ((u128)s64[2] << 64) | s64[3];
  const u128 MULT = ((u128)0x2360ED051FC65DA4ULL << 64) | 0x4385DF649FCCF645ULL;
  u128 state = 0;
  u128 inc = (initseq << 1) | 1;
  state = state * MULT + inc;
  state += initstate;
  state = state * MULT + inc;
  for (int i = 0; i < NN; i++)
    for (int j = 0; j < NN; j++) {
      state = state * MULT + inc;
      uint64_t hi = (uint64_t)(state >> 64), lo = (uint64_t)state;
      unsigned rot = (unsigned)(hi >> 58);
      uint64_t xr = hi ^ lo;
      uint64_t out = (xr >> rot) | (xr << ((64u - rot) & 63u));
      double dv = (double)(out >> 11) * (1.0 / 9007199254740992.0);
      adj[i][j] = (dv < 0.25);
    }
}

// ---------------- device ----------------
struct NodeDesc {
  uint8_t node, npred, slot, flags;
  uint8_t pred_slot[31];
  uint8_t pad;
};
struct GroupArg { int n; NodeDesc d[32]; };   // one launch per LEVEL
struct FinalArg { int nf; uint8_t slot[32]; };

__device__ __forceinline__ float bf2f_lo(unsigned int w) {
  union { unsigned int u; float f; } c; c.u = w << 16; return c.f;
}
__device__ __forceinline__ float bf2f_hi(unsigned int w) {
  union { unsigned int u; float f; } c; c.u = w & 0xFFFF0000u; return c.f;
}
__device__ __forceinline__ float bf2f(unsigned short h) {
  union { unsigned int u; float f; } c; c.u = ((unsigned int)h) << 16; return c.f;
}
__device__ __forceinline__ unsigned short f2bf(float f) {
  union { float f; unsigned int u; } c; c.f = f;
  unsigned int u = c.u + 0x7FFFu + ((c.u >> 16) & 1u);  // RNE
  return (unsigned short)(u >> 16);
}

// R25: node-parallel level launches. Counters (R24: Occ 18%, VALU 12%,
// MFMA 0.3%, HBM 1-5%) showed pure latency-bound: 784 blocks = 3.06/CU and
// nodes within a level ran SERIALLY inside each block (kk loop, 3 barriers
// per node). Nodes in a level are independent -> grid = 784 * n_nodes, one
// (node, tile) per block. Also drops the pw double-buffer (no node loop),
// LDS 36352 -> ~27.8 KB -> 5 blocks/CU cap. Grid keeps node*784 + m*8 + b
// so blockIdx%8 == b (image <-> XCD pinning, 784 % 8 == 0). Per-node code
// (halo aggregation, depthwise, granule-swizzled bf16 MFMA pointwise, BN,
// bf16 slots) unchanged from the verified R18/R24 path.
__global__ __launch_bounds__(256) void level_kernel(
    GroupArg g,
    const float* __restrict__ x,
    const float* __restrict__ dwall,
    const float* __restrict__ pwall,
    const float* __restrict__ gmall,
    const float* __restrict__ btall,
    const float* __restrict__ mnall,
    const float* __restrict__ vrall,
    const float* __restrict__ aggw,
    unsigned short* __restrict__ wsb)   // bf16 slots
{
  __shared__ float smem[3840];                          // halo [6r][10c][64ch] fp32
  __shared__ __align__(16) unsigned short pwb[4096];    // pw weights (bf16, swz)
  __shared__ __align__(16) unsigned short tbuf[2048];   // t[32 pos][64 c] (bf16, swz)
  __shared__ float wlds[32];                            // agg weights

  const int bid = blockIdx.x;
  const int nid = bid / 784;          // node index within this level
  const int r   = bid - nid * 784;
  const int b = r & 7;                // image == XCD
  const int m = r >> 3;               // tile [0,98)
  const int t = threadIdx.x;
  const int ty = (m / 7) * 4;         // 14 y-tiles of 4 rows
  const int tx = (m % 7) * 8;         // 7 x-tiles of 8 cols

  const NodeDesc nd = g.d[nid];
  const int node = nd.node;

  auto stage = [&]() {
    const float* pwn = pwall + node * 4096;
    #pragma unroll
    for (int i = 0; i < 16; i++) {
      int gidx = t + 256 * i;
      int o = gidx >> 6, cc = gidx & 63;
      pwb[o * 64 + ((((cc >> 3) ^ (o & 7)) << 3) | (cc & 7))] = f2bf(pwn[gidx]);
    }
  };

  int dwc, pbase;
  if (nd.npred == 0) { dwc = t >> 2; pbase = (t & 3) * 8; }
  else               { dwc = t & 63; pbase = (t >> 6) * 8; }

  const float* k9 = dwall + (node * 64 + dwc) * 9;
  float kk9[9];
  #pragma unroll
  for (int q = 0; q < 9; q++) kk9[q] = k9[q];

  float tv[8];

  if (nd.npred == 0) {
    // input node: depthwise stride-2 over relu(x), x NCHW [8][64][112][112]
    const float* xb = x + (size_t)(b * 64 + dwc) * 12544;
    #pragma unroll
    for (int jj = 0; jj < 8; jj++) {
      int p = pbase + jj;
      int oy = ty + (p >> 3), ox = tx + (p & 7);
      int iy0 = oy * 2 - 1, ix0 = ox * 2 - 1;
      float s = 0.f;
      #pragma unroll
      for (int dy = 0; dy < 3; dy++) {
        int iy = iy0 + dy;
        if ((unsigned)iy >= 112u) continue;
        const float* row = xb + iy * 112;
        #pragma unroll
        for (int dx = 0; dx < 3; dx++) {
          int ix = ix0 + dx;
          if ((unsigned)ix >= 112u) continue;
          s += fmaxf(row[ix], 0.f) * kk9[dy * 3 + dx];
        }
      }
      tv[jj] = s;
    }
    stage();
  } else {
    // aggregate + relu into fp32 NHWC halo (480 units of 8 ch = 16 B)
    if (t < nd.npred) {
      float wv = 1.f / (1.f + expf(-aggw[node * 32 + t]));
      wlds[t] = (nd.npred == 1) ? 1.0f : wv;
    }
    const int np = nd.npred;
    float sa[2][8];
    int off[2];
    bool inb[2];
    #pragma unroll
    for (int u = 0; u < 2; u++) {
      int idx = t + u * 256;
      bool valid = (u == 0) || (t < 224);
      int pos = idx >> 3, q8 = idx & 7;
      int hy = pos / 10, hx = pos - hy * 10;
      int gy = ty + hy - 1, gx = tx + hx - 1;
      inb[u] = valid && ((unsigned)gy < 56u) && ((unsigned)gx < 56u);
      off[u] = ((b * 56 + gy) * 56 + gx) * 64 + q8 * 8;
      #pragma unroll
      for (int q = 0; q < 8; q++) sa[u][q] = 0.f;
    }
    __syncthreads();   // B1: wlds visible
    for (int p0 = 0; p0 < np; p0 += 4) {
      uint4 v[4][2];
      #pragma unroll
      for (int pp = 0; pp < 4; pp++) {
        if (p0 + pp < np) {
          const unsigned short* pb = wsb + (size_t)nd.pred_slot[p0 + pp] * NODE_ELEMS;
          #pragma unroll
          for (int u = 0; u < 2; u++)
            if (inb[u]) v[pp][u] = *(const uint4*)(pb + off[u]);
        }
      }
      #pragma unroll
      for (int pp = 0; pp < 4; pp++) {
        if (p0 + pp < np) {
          float wv = wlds[p0 + pp];
          #pragma unroll
          for (int u = 0; u < 2; u++) {
            if (inb[u]) {
              sa[u][0] = fmaf(wv, bf2f_lo(v[pp][u].x), sa[u][0]);
              sa[u][1] = fmaf(wv, bf2f_hi(v[pp][u].x), sa[u][1]);
              sa[u][2] = fmaf(wv, bf2f_lo(v[pp][u].y), sa[u][2]);
              sa[u][3] = fmaf(wv, bf2f_hi(v[pp][u].y), sa[u][3]);
              sa[u][4] = fmaf(wv, bf2f_lo(v[pp][u].z), sa[u][4]);
              sa[u][5] = fmaf(wv, bf2f_hi(v[pp][u].z), sa[u][5]);
              sa[u][6] = fmaf(wv, bf2f_lo(v[pp][u].w), sa[u][6]);
              sa[u][7] = fmaf(wv, bf2f_hi(v[pp][u].w), sa[u][7]);
            }
          }
        }
      }
    }
    #pragma unroll
    for (int u = 0; u < 2; u++) {
      int idx = t + u * 256;
      if ((u == 0) || (t < 224)) {
        float4 s0 = make_float4(fmaxf(sa[u][0], 0.f), fmaxf(sa[u][1], 0.f),
                                fmaxf(sa[u][2], 0.f), fmaxf(sa[u][3], 0.f));
        float4 s1 = make_float4(fmaxf(sa[u][4], 0.f), fmaxf(sa[u][5], 0.f),
                                fmaxf(sa[u][6], 0.f), fmaxf(sa[u][7], 0.f));
        *(float4*)&smem[idx * 8] = s0;
        *(float4*)&smem[idx * 8 + 4] = s1;
      }
    }
    stage();           // pw staging overlaps the B2 wait; consumed after B3
    __syncthreads();   // B2: halo ready
    #pragma unroll
    for (int jj = 0; jj < 8; jj++) {
      int p = pbase + jj;
      int py = p >> 3, px = p & 7;
      const float* r0 = smem + (py * 10 + px) * 64 + dwc;
      tv[jj] = r0[0]    * kk9[0] + r0[64]   * kk9[1] + r0[128]  * kk9[2]
             + r0[640]  * kk9[3] + r0[704]  * kk9[4] + r0[768]  * kk9[5]
             + r0[1280] * kk9[6] + r0[1344] * kk9[7] + r0[1408] * kk9[8];
    }
  }

  // t matrix bf16, granule-swizzled: (p,c) -> p*64 + (((c>>3)^(p&7))<<3)|(c&7)
  #pragma unroll
  for (int jj = 0; jj < 8; jj++) {
    int p = pbase + jj;
    tbuf[p * 64 + ((((dwc >> 3) ^ (p & 7)) << 3) | (dwc & 7))] = f2bf(tv[jj]);
  }
  __syncthreads();   // B3: tbuf + pwb ready

  // MFMA pointwise: D[32 pos][64 oc] = t x pw^T
  const int lane = t & 63;
  const int wave = t >> 6;
  const int mtile = wave & 1;
  const int npair = wave >> 1;
  const int lm = lane & 15;
  const int quad = lane >> 4;

  bf16x8 afrag[2];
  #pragma unroll
  for (int ks = 0; ks < 2; ks++) {
    int pos = mtile * 16 + lm;
    int gg = ks * 4 + quad;
    afrag[ks] = *(const bf16x8*)&tbuf[pos * 64 + ((gg ^ (pos & 7)) << 3)];
  }
  f32x4 acc[2];
  #pragma unroll
  for (int nt = 0; nt < 2; nt++) {
    acc[nt] = (f32x4){0.f, 0.f, 0.f, 0.f};
    int oc = (npair * 2 + nt) * 16 + lm;
    #pragma unroll
    for (int ks = 0; ks < 2; ks++) {
      int gg = ks * 4 + quad;
      bf16x8 bfrag = *(const bf16x8*)&pwb[oc * 64 + ((gg ^ (oc & 7)) << 3)];
      acc[nt] = __builtin_amdgcn_mfma_f32_16x16x32_bf16(afrag[ks], bfrag, acc[nt], 0, 0, 0);
    }
  }

  // BN + bf16 slot store. D: col=lane&15 (oc), row=quad*4+reg (pos in tile)
  unsigned short* slotp = wsb + (size_t)nd.slot * NODE_ELEMS;
  #pragma unroll
  for (int nt = 0; nt < 2; nt++) {
    int oc = (npair * 2 + nt) * 16 + lm;
    int gi = node * 64 + oc;
    float inv = gmall[gi] / sqrtf(vrall[gi] + 1e-5f);
    float mn = mnall[gi], btv = btall[gi];
    #pragma unroll
    for (int rr = 0; rr < 4; rr++) {
      int pos = mtile * 16 + quad * 4 + rr;
      int gy = ty + (pos >> 3), gx = tx + (pos & 7);
      size_t base = (((size_t)(b * 56 + gy)) * 56 + gx) * 64 + oc;
      slotp[base] = f2bf((acc[nt][rr] - mn) * inv + btv);
    }
  }
}

// Mean of FINAL bf16 slots (fp32 accumulate) -> NCHW d_out. Block per (b,y) row.
__global__ __launch_bounds__(256) void finalize_kernel(
    FinalArg fa, const unsigned short* __restrict__ wsb,
    float* __restrict__ out, float inv_nf)
{
  __shared__ float lds[57 * 64];
  int by = blockIdx.x;
  int b = by / 56, y = by - b * 56;
  size_t rbase = (((size_t)b * 56 + y) * 56) * 64;  // [x][c]
  for (int i = threadIdx.x; i < 3584; i += 256) {
    float s = 0.f;
    for (int f = 0; f < fa.nf; f++)
      s += bf2f(wsb[(size_t)fa.slot[f] * NODE_ELEMS + rbase + i]);
    int xx = i >> 6, c = i & 63;
    lds[c * 57 + xx] = s * inv_nf;
  }
  __syncthreads();
  float* dst = out + (size_t)b * 64 * 3136 + y * 56;
  for (int i = threadIdx.x; i < 3584; i += 256) {
    int c = i / 56, xx = i - c * 56;
    dst[(size_t)c * 3136 + xx] = lds[c * 57 + xx];
  }
}

// ---------------- launcher ----------------
extern "C" void kernel_launch(void* const* d_in, const int* in_sizes, int n_in,
                              void* d_out, int out_size, void* d_ws, size_t ws_size,
                              hipStream_t stream) {
  (void)in_sizes; (void)n_in; (void)ws_size; (void)out_size;
  const float* x     = (const float*)d_in[0];
  const float* dw    = (const float*)d_in[1];
  const float* pw    = (const float*)d_in[2];
  const float* gamma = (const float*)d_in[3];
  const float* beta  = (const float*)d_in[4];
  const float* mean  = (const float*)d_in[5];
  const float* var   = (const float*)d_in[6];
  const float* aggw  = (const float*)d_in[7];
  unsigned short* wsb = (unsigned short*)d_ws;
  float* out = (float*)d_out;

  bool adj[NN][NN];
  compute_adj(adj);

  int npred[NN], preds[NN][NN], nsucc[NN], ispan[NN], level[NN];
  for (int j = 0; j < NN; j++) {
    npred[j] = 0;
    for (int i = 0; i < j; i++) if (adj[i][j]) preds[j][npred[j]++] = i;
  }
  for (int i = 0; i < NN; i++) {
    nsucc[i] = 0; ispan[i] = NN;
    int mx = -1;
    for (int j = i + 1; j < NN; j++) if (adj[i][j]) { nsucc[i]++; mx = j; }
    if (nsucc[i] > 0) ispan[i] = mx;
  }
  int maxlev = 0;
  for (int j = 0; j < NN; j++) {
    int lv = 0;
    for (int p = 0; p < npred[j]; p++) {
      int cand = level[preds[j][p]] + 1;
      if (cand > lv) lv = cand;
    }
    level[j] = lv;
    if (lv > maxlev) maxlev = lv;
  }
  bool isfinal[NN]; int nf = 0;
  for (int i = 0; i < NN; i++) { isfinal[i] = (ispan[i] >= NN - 1); if (isfinal[i]) nf++; }
  int lastlvl[NN];
  for (int i = 0; i < NN; i++) {
    lastlvl[i] = -1;
    for (int j = i + 1; j < NN; j++) if (adj[i][j] && level[j] > lastlvl[i]) lastlvl[i] = level[j];
  }
  // slot allocation: every node gets a slot; FINAL slots never freed.
  int slot[NN]; bool used[NN];
  for (int s = 0; s < NN; s++) used[s] = false;
  for (int L = 0; L <= maxlev; L++) {
    for (int i = 0; i < NN; i++) {
      if (level[i] != L) continue;
      int s = 0; while (used[s]) s++;
      used[s] = true; slot[i] = s;
    }
    for (int i = 0; i < NN; i++)
      if (level[i] <= L && !isfinal[i] && lastlvl[i] == L)
        used[slot[i]] = false;
  }

  float inv_nf = 1.0f / (float)nf;

  for (int L = 0; L <= maxlev; L++) {
    GroupArg g; g.n = 0;
    for (int i = 0; i < NN; i++) {
      if (level[i] != L) continue;
      NodeDesc& nd = g.d[g.n++];
      nd.node = (uint8_t)i;
      nd.npred = (uint8_t)npred[i];
      nd.slot = (uint8_t)slot[i];
      nd.flags = 0;
      for (int p = 0; p < npred[i]; p++) nd.pred_slot[p] = (uint8_t)slot[preds[i][p]];
    }
    if (g.n > 0) {
      level_kernel<<<784 * g.n, 256, 0, stream>>>(g, x, dw, pw, gamma, beta,
                                                  mean, var, aggw, wsb);
    }
  }

  FinalArg fa; fa.nf = 0;
  for (int i = 0; i < NN; i++) if (isfinal[i]) fa.slot[fa.nf++] = (uint8_t)slot[i];
  finalize_kernel<<<448, 256, 0, stream>>>(fa, wsb, out, inv_nf);
}

// Round 2
// 300.150 us; speedup vs baseline: 2.0289x; 2.0289x over previous
//
#include <hip/hip_runtime.h>
#include <cstdint>
#include <cstddef>

#define NN 32
#define NODE_ELEMS 1605632  // 8*56*56*64 elements per slot (NHWC); bf16 storage

typedef unsigned __int128 u128;
typedef __attribute__((ext_vector_type(8))) short bf16x8;
typedef __attribute__((ext_vector_type(4))) float f32x4;

// ---------------- host: replicate np.random.default_rng(0).random((32,32)) < 0.25 ----
static void compute_adj(bool adj[NN][NN]) {
  uint32_t pool[4];
  uint32_t hc = 0x43b0d7e5u;
  auto hashmix = [&hc](uint32_t v) -> uint32_t {
    v ^= hc; hc *= 0x931e8875u; v *= hc; v ^= v >> 16; return v;
  };
  auto mix = [](uint32_t x, uint32_t y) -> uint32_t {
    uint32_t r = x * 0xca01f9ddu - y * 0x4973f715u; r ^= r >> 16; return r;
  };
  for (int i = 0; i < 4; i++) pool[i] = hashmix(0u);
  for (int s = 0; s < 4; s++)
    for (int d = 0; d < 4; d++)
      if (s != d) pool[d] = mix(pool[d], hashmix(pool[s]));
  uint32_t hb = 0x8b51f9ddu;
  uint32_t w[8];
  for (int k = 0; k < 8; k++) {
    uint32_t v = pool[k & 3];
    v ^= hb; hb *= 0x58f38dedu; v *= hb; v ^= v >> 16;
    w[k] = v;
  }
  uint64_t s64[4];
  for (int j = 0; j < 4; j++) s64[j] = (uint64_t)w[2 * j] | ((uint64_t)w[2 * j + 1] << 32);
  u128 initstate = ((u128)s64[0] << 64) | s64[1];
  u128 initseq   = ((u128)s64[2] << 64) | s64[3];
  const u128 MULT = ((u128)0x2360ED051FC65DA4ULL << 64) | 0x4385DF649FCCF645ULL;
  u128 state = 0;
  u128 inc = (initseq << 1) | 1;
  state = state * MULT + inc;
  state += initstate;
  state = state * MULT + inc;
  for (int i = 0; i < NN; i++)
    for (int j = 0; j < NN; j++) {
      state = state * MULT + inc;
      uint64_t hi = (uint64_t)(state >> 64), lo = (uint64_t)state;
      unsigned rot = (unsigned)(hi >> 58);
      uint64_t xr = hi ^ lo;
      uint64_t out = (xr >> rot) | (xr << ((64u - rot) & 63u));
      double dv = (double)(out >> 11) * (1.0 / 9007199254740992.0);
      adj[i][j] = (dv < 0.25);
    }
}

// ---------------- device ----------------
struct NodeDesc {
  uint8_t node, npred, slot, flags;
  uint8_t pred_slot[31];
  uint8_t pad;
};
struct GroupArg { int n; NodeDesc d[32]; };   // one launch per LEVEL
struct FinalArg { int nf; uint8_t slot[32]; };

__device__ __forceinline__ float bf2f_lo(unsigned int w) {
  union { unsigned int u; float f; } c; c.u = w << 16; return c.f;
}
__device__ __forceinline__ float bf2f_hi(unsigned int w) {
  union { unsigned int u; float f; } c; c.u = w & 0xFFFF0000u; return c.f;
}
__device__ __forceinline__ float bf2f(unsigned short h) {
  union { unsigned int u; float f; } c; c.u = ((unsigned int)h) << 16; return c.f;
}
__device__ __forceinline__ unsigned short f2bf(float f) {
  union { float f; unsigned int u; } c; c.f = f;
  unsigned int u = c.u + 0x7FFFu + ((c.u >> 16) & 1u);  // RNE
  return (unsigned short)(u >> 16);
}

// R26: hybrid.
// R25 counters decomposed: the recurring 370us dispatch (ords 11,770,781,...,
// spacing 11 = dispatches/iter) is LEVEL 0 (input nodes); FETCH 22.5MB == one
// full read of x. Node-parallelism made level 0 re-stream the 3.2MB per-XCD
// x-slice n times through L2 (R24's node-serial block re-read a 39KB L1-hot
// region instead). Meanwhile levels >=1 IMPROVED 364us -> 239us under
// node-parallelism. So: keep node-parallel level_kernel for levels >= 1;
// add input_kernel for level 0 that stages relu(x) tile in LDS ONCE and loops
// the input nodes over it (they all share x). x read once per block region;
// per-node work is LDS depthwise + MFMA pointwise only.
__global__ __launch_bounds__(256) void input_kernel(
    GroupArg g,
    const float* __restrict__ x,
    const float* __restrict__ dwall,
    const float* __restrict__ pwall,
    const float* __restrict__ gmall,
    const float* __restrict__ btall,
    const float* __restrict__ mnall,
    const float* __restrict__ vrall,
    unsigned short* __restrict__ wsb)
{
  __shared__ float xtile[9 * 17 * 64];                  // [9r][17c][64ch] relu(x) fp32
  __shared__ __align__(16) unsigned short pwb[4096];    // pw weights (bf16, swz)
  __shared__ __align__(16) unsigned short tbuf[2048];   // t[32 pos][64 c] (bf16, swz)

  const int b = blockIdx.x & 7;       // image == XCD
  const int m = blockIdx.x >> 3;      // tile [0,98)
  const int t = threadIdx.x;
  const int ty = (m / 7) * 4;         // 14 y-tiles of 4 rows (output 56x56)
  const int tx = (m % 7) * 8;         // 7 x-tiles of 8 cols

  const int dwc = t & 63;
  const int pbase = (t >> 6) * 8;

  // ---- stage relu(x) tile once: input rows 2ty-1..2ty+7, cols 2tx-1..2tx+15
  {
    const int r0 = t >> 6;
    const float* xb = x + (size_t)(b * 64 + dwc) * 12544;
    const int iy0 = ty * 2 - 1, ix0 = tx * 2 - 1;
    for (int iyL = r0; iyL < 9; iyL += 4) {
      int gy = iy0 + iyL;
      bool rowok = ((unsigned)gy < 112u);
      const float* row = xb + gy * 112;
      float* dst = xtile + (iyL * 17) * 64 + dwc;
      #pragma unroll
      for (int ixL = 0; ixL < 17; ixL++) {
        int gx = ix0 + ixL;
        float v = 0.f;
        if (rowok && ((unsigned)gx < 112u)) v = fmaxf(row[gx], 0.f);
        dst[ixL * 64] = v;   // lanes = consecutive ch -> conflict-free
      }
    }
  }

  for (int kk = 0; kk < g.n; kk++) {
    const NodeDesc nd = g.d[kk];
    const int node = nd.node;

    __syncthreads();  // B_a: xtile ready (kk=0); prev MFMA done with pwb/tbuf

    // stage pw (issue global loads early; latency hides under depthwise VALU)
    {
      const float* pwn = pwall + node * 4096;
      #pragma unroll
      for (int i = 0; i < 16; i++) {
        int gidx = t + 256 * i;
        int o = gidx >> 6, cc = gidx & 63;
        pwb[o * 64 + ((((cc >> 3) ^ (o & 7)) << 3) | (cc & 7))] = f2bf(pwn[gidx]);
      }
    }

    const float* k9 = dwall + (node * 64 + dwc) * 9;
    float kk9[9];
    #pragma unroll
    for (int q = 0; q < 9; q++) kk9[q] = k9[q];

    // depthwise stride-2 from LDS xtile
    float tv[8];
    #pragma unroll
    for (int jj = 0; jj < 8; jj++) {
      int p = pbase + jj;
      int py = p >> 3, px = p & 7;
      const float* r0 = xtile + ((py * 2) * 17 + px * 2) * 64 + dwc;
      tv[jj] = r0[0]    * kk9[0] + r0[64]   * kk9[1] + r0[128]  * kk9[2]
             + r0[1088] * kk9[3] + r0[1152] * kk9[4] + r0[1216] * kk9[5]
             + r0[2176] * kk9[6] + r0[2240] * kk9[7] + r0[2304] * kk9[8];
    }

    // t matrix bf16, granule-swizzled
    #pragma unroll
    for (int jj = 0; jj < 8; jj++) {
      int p = pbase + jj;
      tbuf[p * 64 + ((((dwc >> 3) ^ (p & 7)) << 3) | (dwc & 7))] = f2bf(tv[jj]);
    }
    __syncthreads();  // B_b: tbuf + pwb ready

    // MFMA pointwise: D[32 pos][64 oc] = t x pw^T
    const int lane = t & 63;
    const int wave = t >> 6;
    const int mtile = wave & 1;
    const int npair = wave >> 1;
    const int lm = lane & 15;
    const int quad = lane >> 4;

    bf16x8 afrag[2];
    #pragma unroll
    for (int ks = 0; ks < 2; ks++) {
      int pos = mtile * 16 + lm;
      int gg = ks * 4 + quad;
      afrag[ks] = *(const bf16x8*)&tbuf[pos * 64 + ((gg ^ (pos & 7)) << 3)];
    }
    f32x4 acc[2];
    #pragma unroll
    for (int nt = 0; nt < 2; nt++) {
      acc[nt] = (f32x4){0.f, 0.f, 0.f, 0.f};
      int oc = (npair * 2 + nt) * 16 + lm;
      #pragma unroll
      for (int ks = 0; ks < 2; ks++) {
        int gg = ks * 4 + quad;
        bf16x8 bfrag = *(const bf16x8*)&pwb[oc * 64 + ((gg ^ (oc & 7)) << 3)];
        acc[nt] = __builtin_amdgcn_mfma_f32_16x16x32_bf16(afrag[ks], bfrag, acc[nt], 0, 0, 0);
      }
    }

    // BN + bf16 slot store
    unsigned short* slotp = wsb + (size_t)nd.slot * NODE_ELEMS;
    #pragma unroll
    for (int nt = 0; nt < 2; nt++) {
      int oc = (npair * 2 + nt) * 16 + lm;
      int gi = node * 64 + oc;
      float inv = gmall[gi] / sqrtf(vrall[gi] + 1e-5f);
      float mn = mnall[gi], btv = btall[gi];
      #pragma unroll
      for (int rr = 0; rr < 4; rr++) {
        int pos = mtile * 16 + quad * 4 + rr;
        int gy = ty + (pos >> 3), gx = tx + (pos & 7);
        size_t base = (((size_t)(b * 56 + gy)) * 56 + gx) * 64 + oc;
        slotp[base] = f2bf((acc[nt][rr] - mn) * inv + btv);
      }
    }
  }
}

// Levels >= 1: node-parallel, one (node, tile) per block. All nodes here have
// npred >= 1 (npred==0 <=> level 0), so the input branch is gone.
__global__ __launch_bounds__(256) void level_kernel(
    GroupArg g,
    const float* __restrict__ dwall,
    const float* __restrict__ pwall,
    const float* __restrict__ gmall,
    const float* __restrict__ btall,
    const float* __restrict__ mnall,
    const float* __restrict__ vrall,
    const float* __restrict__ aggw,
    unsigned short* __restrict__ wsb)   // bf16 slots
{
  __shared__ float smem[3840];                          // halo [6r][10c][64ch] fp32
  __shared__ __align__(16) unsigned short pwb[4096];    // pw weights (bf16, swz)
  __shared__ __align__(16) unsigned short tbuf[2048];   // t[32 pos][64 c] (bf16, swz)
  __shared__ float wlds[32];                            // agg weights

  const int bid = blockIdx.x;
  const int nid = bid / 784;          // node index within this level
  const int r   = bid - nid * 784;
  const int b = r & 7;                // image == XCD
  const int m = r >> 3;               // tile [0,98)
  const int t = threadIdx.x;
  const int ty = (m / 7) * 4;         // 14 y-tiles of 4 rows
  const int tx = (m % 7) * 8;         // 7 x-tiles of 8 cols

  const NodeDesc nd = g.d[nid];
  const int node = nd.node;

  const int dwc = t & 63;
  const int pbase = (t >> 6) * 8;

  const float* k9 = dwall + (node * 64 + dwc) * 9;
  float kk9[9];
  #pragma unroll
  for (int q = 0; q < 9; q++) kk9[q] = k9[q];

  float tv[8];

  // aggregate + relu into fp32 NHWC halo (480 units of 8 ch = 16 B)
  if (t < nd.npred) {
    float wv = 1.f / (1.f + expf(-aggw[node * 32 + t]));
    wlds[t] = (nd.npred == 1) ? 1.0f : wv;
  }
  const int np = nd.npred;
  float sa[2][8];
  int off[2];
  bool inb[2];
  #pragma unroll
  for (int u = 0; u < 2; u++) {
    int idx = t + u * 256;
    bool valid = (u == 0) || (t < 224);
    int pos = idx >> 3, q8 = idx & 7;
    int hy = pos / 10, hx = pos - hy * 10;
    int gy = ty + hy - 1, gx = tx + hx - 1;
    inb[u] = valid && ((unsigned)gy < 56u) && ((unsigned)gx < 56u);
    off[u] = ((b * 56 + gy) * 56 + gx) * 64 + q8 * 8;
    #pragma unroll
    for (int q = 0; q < 8; q++) sa[u][q] = 0.f;
  }
  __syncthreads();   // B1: wlds visible
  for (int p0 = 0; p0 < np; p0 += 4) {
    uint4 v[4][2];
    #pragma unroll
    for (int pp = 0; pp < 4; pp++) {
      if (p0 + pp < np) {
        const unsigned short* pb = wsb + (size_t)nd.pred_slot[p0 + pp] * NODE_ELEMS;
        #pragma unroll
        for (int u = 0; u < 2; u++)
          if (inb[u]) v[pp][u] = *(const uint4*)(pb + off[u]);
      }
    }
    #pragma unroll
    for (int pp = 0; pp < 4; pp++) {
      if (p0 + pp < np) {
        float wv = wlds[p0 + pp];
        #pragma unroll
        for (int u = 0; u < 2; u++) {
          if (inb[u]) {
            sa[u][0] = fmaf(wv, bf2f_lo(v[pp][u].x), sa[u][0]);
            sa[u][1] = fmaf(wv, bf2f_hi(v[pp][u].x), sa[u][1]);
            sa[u][2] = fmaf(wv, bf2f_lo(v[pp][u].y), sa[u][2]);
            sa[u][3] = fmaf(wv, bf2f_hi(v[pp][u].y), sa[u][3]);
            sa[u][4] = fmaf(wv, bf2f_lo(v[pp][u].z), sa[u][4]);
            sa[u][5] = fmaf(wv, bf2f_hi(v[pp][u].z), sa[u][5]);
            sa[u][6] = fmaf(wv, bf2f_lo(v[pp][u].w), sa[u][6]);
            sa[u][7] = fmaf(wv, bf2f_hi(v[pp][u].w), sa[u][7]);
          }
        }
      }
    }
  }
  #pragma unroll
  for (int u = 0; u < 2; u++) {
    int idx = t + u * 256;
    if ((u == 0) || (t < 224)) {
      float4 s0 = make_float4(fmaxf(sa[u][0], 0.f), fmaxf(sa[u][1], 0.f),
                              fmaxf(sa[u][2], 0.f), fmaxf(sa[u][3], 0.f));
      float4 s1 = make_float4(fmaxf(sa[u][4], 0.f), fmaxf(sa[u][5], 0.f),
                              fmaxf(sa[u][6], 0.f), fmaxf(sa[u][7], 0.f));
      *(float4*)&smem[idx * 8] = s0;
      *(float4*)&smem[idx * 8 + 4] = s1;
    }
  }
  // stage pw (overlaps the B2 wait; consumed after B3)
  {
    const float* pwn = pwall + node * 4096;
    #pragma unroll
    for (int i = 0; i < 16; i++) {
      int gidx = t + 256 * i;
      int o = gidx >> 6, cc = gidx & 63;
      pwb[o * 64 + ((((cc >> 3) ^ (o & 7)) << 3) | (cc & 7))] = f2bf(pwn[gidx]);
    }
  }
  __syncthreads();   // B2: halo ready
  #pragma unroll
  for (int jj = 0; jj < 8; jj++) {
    int p = pbase + jj;
    int py = p >> 3, px = p & 7;
    const float* r0 = smem + (py * 10 + px) * 64 + dwc;
    tv[jj] = r0[0]    * kk9[0] + r0[64]   * kk9[1] + r0[128]  * kk9[2]
           + r0[640]  * kk9[3] + r0[704]  * kk9[4] + r0[768]  * kk9[5]
           + r0[1280] * kk9[6] + r0[1344] * kk9[7] + r0[1408] * kk9[8];
  }

  // t matrix bf16, granule-swizzled: (p,c) -> p*64 + (((c>>3)^(p&7))<<3)|(c&7)
  #pragma unroll
  for (int jj = 0; jj < 8; jj++) {
    int p = pbase + jj;
    tbuf[p * 64 + ((((dwc >> 3) ^ (p & 7)) << 3) | (dwc & 7))] = f2bf(tv[jj]);
  }
  __syncthreads();   // B3: tbuf + pwb ready

  // MFMA pointwise: D[32 pos][64 oc] = t x pw^T
  const int lane = t & 63;
  const int wave = t >> 6;
  const int mtile = wave & 1;
  const int npair = wave >> 1;
  const int lm = lane & 15;
  const int quad = lane >> 4;

  bf16x8 afrag[2];
  #pragma unroll
  for (int ks = 0; ks < 2; ks++) {
    int pos = mtile * 16 + lm;
    int gg = ks * 4 + quad;
    afrag[ks] = *(const bf16x8*)&tbuf[pos * 64 + ((gg ^ (pos & 7)) << 3)];
  }
  f32x4 acc[2];
  #pragma unroll
  for (int nt = 0; nt < 2; nt++) {
    acc[nt] = (f32x4){0.f, 0.f, 0.f, 0.f};
    int oc = (npair * 2 + nt) * 16 + lm;
    #pragma unroll
    for (int ks = 0; ks < 2; ks++) {
      int gg = ks * 4 + quad;
      bf16x8 bfrag = *(const bf16x8*)&pwb[oc * 64 + ((gg ^ (oc & 7)) << 3)];
      acc[nt] = __builtin_amdgcn_mfma_f32_16x16x32_bf16(afrag[ks], bfrag, acc[nt], 0, 0, 0);
    }
  }

  // BN + bf16 slot store. D: col=lane&15 (oc), row=quad*4+reg (pos in tile)
  unsigned short* slotp = wsb + (size_t)nd.slot * NODE_ELEMS;
  #pragma unroll
  for (int nt = 0; nt < 2; nt++) {
    int oc = (npair * 2 + nt) * 16 + lm;
    int gi = node * 64 + oc;
    float inv = gmall[gi] / sqrtf(vrall[gi] + 1e-5f);
    float mn = mnall[gi], btv = btall[gi];
    #pragma unroll
    for (int rr = 0; rr < 4; rr++) {
      int pos = mtile * 16 + quad * 4 + rr;
      int gy = ty + (pos >> 3), gx = tx + (pos & 7);
      size_t base = (((size_t)(b * 56 + gy)) * 56 + gx) * 64 + oc;
      slotp[base] = f2bf((acc[nt][rr] - mn) * inv + btv);
    }
  }
}

// Mean of FINAL bf16 slots (fp32 accumulate) -> NCHW d_out. Block per (b,y) row.
__global__ __launch_bounds__(256) void finalize_kernel(
    FinalArg fa, const unsigned short* __restrict__ wsb,
    float* __restrict__ out, float inv_nf)
{
  __shared__ float lds[57 * 64];
  int by = blockIdx.x;
  int b = by / 56, y = by - b * 56;
  size_t rbase = (((size_t)b * 56 + y) * 56) * 64;  // [x][c]
  for (int i = threadIdx.x; i < 3584; i += 256) {
    float s = 0.f;
    for (int f = 0; f < fa.nf; f++)
      s += bf2f(wsb[(size_t)fa.slot[f] * NODE_ELEMS + rbase + i]);
    int xx = i >> 6, c = i & 63;
    lds[c * 57 + xx] = s * inv_nf;
  }
  __syncthreads();
  float* dst = out + (size_t)b * 64 * 3136 + y * 56;
  for (int i = threadIdx.x; i < 3584; i += 256) {
    int c = i / 56, xx = i - c * 56;
    dst[(size_t)c * 3136 + xx] = lds[c * 57 + xx];
  }
}

// ---------------- launcher ----------------
extern "C" void kernel_launch(void* const* d_in, const int* in_sizes, int n_in,
                              void* d_out, int out_size, void* d_ws, size_t ws_size,
                              hipStream_t stream) {
  (void)in_sizes; (void)n_in; (void)ws_size; (void)out_size;
  const float* x     = (const float*)d_in[0];
  const float* dw    = (const float*)d_in[1];
  const float* pw    = (const float*)d_in[2];
  const float* gamma = (const float*)d_in[3];
  const float* beta  = (const float*)d_in[4];
  const float* mean  = (const float*)d_in[5];
  const float* var   = (const float*)d_in[6];
  const float* aggw  = (const float*)d_in[7];
  unsigned short* wsb = (unsigned short*)d_ws;
  float* out = (float*)d_out;

  bool adj[NN][NN];
  compute_adj(adj);

  int npred[NN], preds[NN][NN], nsucc[NN], ispan[NN], level[NN];
  for (int j = 0; j < NN; j++) {
    npred[j] = 0;
    for (int i = 0; i < j; i++) if (adj[i][j]) preds[j][npred[j]++] = i;
  }
  for (int i = 0; i < NN; i++) {
    nsucc[i] = 0; ispan[i] = NN;
    int mx = -1;
    for (int j = i + 1; j < NN; j++) if (adj[i][j]) { nsucc[i]++; mx = j; }
    if (nsucc[i] > 0) ispan[i] = mx;
  }
  int maxlev = 0;
  for (int j = 0; j < NN; j++) {
    int lv = 0;
    for (int p = 0; p < npred[j]; p++) {
      int cand = level[preds[j][p]] + 1;
      if (cand > lv) lv = cand;
    }
    level[j] = lv;
    if (lv > maxlev) maxlev = lv;
  }
  bool isfinal[NN]; int nf = 0;
  for (int i = 0; i < NN; i++) { isfinal[i] = (ispan[i] >= NN - 1); if (isfinal[i]) nf++; }
  int lastlvl[NN];
  for (int i = 0; i < NN; i++) {
    lastlvl[i] = -1;
    for (int j = i + 1; j < NN; j++) if (adj[i][j] && level[j] > lastlvl[i]) lastlvl[i] = level[j];
  }
  // slot allocation: every node gets a slot; FINAL slots never freed.
  int slot[NN]; bool used[NN];
  for (int s = 0; s < NN; s++) used[s] = false;
  for (int L = 0; L <= maxlev; L++) {
    for (int i = 0; i < NN; i++) {
      if (level[i] != L) continue;
      int s = 0; while (used[s]) s++;
      used[s] = true; slot[i] = s;
    }
    for (int i = 0; i < NN; i++)
      if (level[i] <= L && !isfinal[i] && lastlvl[i] == L)
        used[slot[i]] = false;
  }

  float inv_nf = 1.0f / (float)nf;

  for (int L = 0; L <= maxlev; L++) {
    GroupArg g; g.n = 0;
    for (int i = 0; i < NN; i++) {
      if (level[i] != L) continue;
      NodeDesc& nd = g.d[g.n++];
      nd.node = (uint8_t)i;
      nd.npred = (uint8_t)npred[i];
      nd.slot = (uint8_t)slot[i];
      nd.flags = 0;
      for (int p = 0; p < npred[i]; p++) nd.pred_slot[p] = (uint8_t)slot[preds[i][p]];
    }
    if (g.n > 0) {
      if (L == 0) {
        input_kernel<<<784, 256, 0, stream>>>(g, x, dw, pw, gamma, beta,
                                              mean, var, wsb);
      } else {
        level_kernel<<<784 * g.n, 256, 0, stream>>>(g, dw, pw, gamma, beta,
                                                    mean, var, aggw, wsb);
      }
    }
  }

  FinalArg fa; fa.nf = 0;
  for (int i = 0; i < NN; i++) if (isfinal[i]) fa.slot[fa.nf++] = (uint8_t)slot[i];
  finalize_kernel<<<448, 256, 0, stream>>>(fa, wsb, out, inv_nf);
}

// Round 3
// 236.679 us; speedup vs baseline: 2.5729x; 1.2682x over previous
//
#include <hip/hip_runtime.h>
#include <cstdint>
#include <cstddef>

#define NN 32
#define NODE_ELEMS 1605632  // 8*56*56*64 elements per slot (NHWC); bf16 storage

typedef unsigned __int128 u128;
typedef __attribute__((ext_vector_type(8))) short bf16x8;
typedef __attribute__((ext_vector_type(4))) float f32x4;

// ---------------- host: replicate np.random.default_rng(0).random((32,32)) < 0.25 ----
static void compute_adj(bool adj[NN][NN]) {
  uint32_t pool[4];
  uint32_t hc = 0x43b0d7e5u;
  auto hashmix = [&hc](uint32_t v) -> uint32_t {
    v ^= hc; hc *= 0x931e8875u; v *= hc; v ^= v >> 16; return v;
  };
  auto mix = [](uint32_t x, uint32_t y) -> uint32_t {
    uint32_t r = x * 0xca01f9ddu - y * 0x4973f715u; r ^= r >> 16; return r;
  };
  for (int i = 0; i < 4; i++) pool[i] = hashmix(0u);
  for (int s = 0; s < 4; s++)
    for (int d = 0; d < 4; d++)
      if (s != d) pool[d] = mix(pool[d], hashmix(pool[s]));
  uint32_t hb = 0x8b51f9ddu;
  uint32_t w[8];
  for (int k = 0; k < 8; k++) {
    uint32_t v = pool[k & 3];
    v ^= hb; hb *= 0x58f38dedu; v *= hb; v ^= v >> 16;
    w[k] = v;
  }
  uint64_t s64[4];
  for (int j = 0; j < 4; j++) s64[j] = (uint64_t)w[2 * j] | ((uint64_t)w[2 * j + 1] << 32);
  u128 initstate = ((u128)s64[0] << 64) | s64[1];
  u128 initseq   = ((u128)s64[2] << 64) | s64[3];
  const u128 MULT = ((u128)0x2360ED051FC65DA4ULL << 64) | 0x4385DF649FCCF645ULL;
  u128 state = 0;
  u128 inc = (initseq << 1) | 1;
  state = state * MULT + inc;
  state += initstate;
  state = state * MULT + inc;
  for (int i = 0; i < NN; i++)
    for (int j = 0; j < NN; j++) {
      state = state * MULT + inc;
      uint64_t hi = (uint64_t)(state >> 64), lo = (uint64_t)state;
      unsigned rot = (unsigned)(hi >> 58);
      uint64_t xr = hi ^ lo;
      uint64_t out = (xr >> rot) | (xr << ((64u - rot) & 63u));
      double dv = (double)(out >> 11) * (1.0 / 9007199254740992.0);
      adj[i][j] = (dv < 0.25);
    }
}

// ---------------- device ----------------
struct NodeDesc {
  uint8_t node, npred, slot, flags;
  uint8_t pred_slot[31];
  uint8_t pad;
};
struct GroupArg { int n; NodeDesc d[32]; };   // one launch per LEVEL
struct FinalArg { int nf; uint8_t slot[32]; };

__device__ __forceinline__ float bf2f_lo(unsigned int w) {
  union { unsigned int u; float f; } c; c.u = w << 16; return c.f;
}
__device__ __forceinline__ float bf2f_hi(unsigned int w) {
  union { unsigned int u; float f; } c; c.u = w & 0xFFFF0000u; return c.f;
}
__device__ __forceinline__ float bf2f(unsigned short h) {
  union { unsigned int u; float f; } c; c.u = ((unsigned int)h) << 16; return c.f;
}
__device__ __forceinline__ unsigned short f2bf(float f) {
  union { float f; unsigned int u; } c; c.f = f;
  unsigned int u = c.u + 0x7FFFu + ((c.u >> 16) & 1u);  // RNE
  return (unsigned short)(u >> 16);
}

// R27: finalize rewrite. R26 counters: all top-5 dispatches were
// finalize_kernel at 74us (25% of the 300us total), VGPR_Count=8,
// 304 GB/s (3.8% peak). Scalar 2B bf16 loads in a rolled f-loop with 8
// VGPRs = 1 load in flight per thread, 448 blocks = 1.75/CU. Roofline is
// 22.5MB @ 6.3TB/s = 3.6us. Fix: uint4 loads (8 bf16/lane), slot loop
// batched 4-wide into NAMED regs (4 loads in flight), 896 blocks
// (half-row each, 3.5/CU), 7.4KB LDS. Accumulation order over f unchanged
// (plain fp32 adds, ascending f) -> bit-identical to R26's finalize.
// input_kernel / level_kernel untouched (verified R26 path).
__global__ __launch_bounds__(256) void input_kernel(
    GroupArg g,
    const float* __restrict__ x,
    const float* __restrict__ dwall,
    const float* __restrict__ pwall,
    const float* __restrict__ gmall,
    const float* __restrict__ btall,
    const float* __restrict__ mnall,
    const float* __restrict__ vrall,
    unsigned short* __restrict__ wsb)
{
  __shared__ float xtile[9 * 17 * 64];                  // [9r][17c][64ch] relu(x) fp32
  __shared__ __align__(16) unsigned short pwb[4096];    // pw weights (bf16, swz)
  __shared__ __align__(16) unsigned short tbuf[2048];   // t[32 pos][64 c] (bf16, swz)

  const int b = blockIdx.x & 7;       // image == XCD
  const int m = blockIdx.x >> 3;      // tile [0,98)
  const int t = threadIdx.x;
  const int ty = (m / 7) * 4;         // 14 y-tiles of 4 rows (output 56x56)
  const int tx = (m % 7) * 8;         // 7 x-tiles of 8 cols

  const int dwc = t & 63;
  const int pbase = (t >> 6) * 8;

  // ---- stage relu(x) tile once: input rows 2ty-1..2ty+7, cols 2tx-1..2tx+15
  {
    const int r0 = t >> 6;
    const float* xb = x + (size_t)(b * 64 + dwc) * 12544;
    const int iy0 = ty * 2 - 1, ix0 = tx * 2 - 1;
    for (int iyL = r0; iyL < 9; iyL += 4) {
      int gy = iy0 + iyL;
      bool rowok = ((unsigned)gy < 112u);
      const float* row = xb + gy * 112;
      float* dst = xtile + (iyL * 17) * 64 + dwc;
      #pragma unroll
      for (int ixL = 0; ixL < 17; ixL++) {
        int gx = ix0 + ixL;
        float v = 0.f;
        if (rowok && ((unsigned)gx < 112u)) v = fmaxf(row[gx], 0.f);
        dst[ixL * 64] = v;   // lanes = consecutive ch -> conflict-free
      }
    }
  }

  for (int kk = 0; kk < g.n; kk++) {
    const NodeDesc nd = g.d[kk];
    const int node = nd.node;

    __syncthreads();  // B_a: xtile ready (kk=0); prev MFMA done with pwb/tbuf

    // stage pw (issue global loads early; latency hides under depthwise VALU)
    {
      const float* pwn = pwall + node * 4096;
      #pragma unroll
      for (int i = 0; i < 16; i++) {
        int gidx = t + 256 * i;
        int o = gidx >> 6, cc = gidx & 63;
        pwb[o * 64 + ((((cc >> 3) ^ (o & 7)) << 3) | (cc & 7))] = f2bf(pwn[gidx]);
      }
    }

    const float* k9 = dwall + (node * 64 + dwc) * 9;
    float kk9[9];
    #pragma unroll
    for (int q = 0; q < 9; q++) kk9[q] = k9[q];

    // depthwise stride-2 from LDS xtile
    float tv[8];
    #pragma unroll
    for (int jj = 0; jj < 8; jj++) {
      int p = pbase + jj;
      int py = p >> 3, px = p & 7;
      const float* r0 = xtile + ((py * 2) * 17 + px * 2) * 64 + dwc;
      tv[jj] = r0[0]    * kk9[0] + r0[64]   * kk9[1] + r0[128]  * kk9[2]
             + r0[1088] * kk9[3] + r0[1152] * kk9[4] + r0[1216] * kk9[5]
             + r0[2176] * kk9[6] + r0[2240] * kk9[7] + r0[2304] * kk9[8];
    }

    // t matrix bf16, granule-swizzled
    #pragma unroll
    for (int jj = 0; jj < 8; jj++) {
      int p = pbase + jj;
      tbuf[p * 64 + ((((dwc >> 3) ^ (p & 7)) << 3) | (dwc & 7))] = f2bf(tv[jj]);
    }
    __syncthreads();  // B_b: tbuf + pwb ready

    // MFMA pointwise: D[32 pos][64 oc] = t x pw^T
    const int lane = t & 63;
    const int wave = t >> 6;
    const int mtile = wave & 1;
    const int npair = wave >> 1;
    const int lm = lane & 15;
    const int quad = lane >> 4;

    bf16x8 afrag[2];
    #pragma unroll
    for (int ks = 0; ks < 2; ks++) {
      int pos = mtile * 16 + lm;
      int gg = ks * 4 + quad;
      afrag[ks] = *(const bf16x8*)&tbuf[pos * 64 + ((gg ^ (pos & 7)) << 3)];
    }
    f32x4 acc[2];
    #pragma unroll
    for (int nt = 0; nt < 2; nt++) {
      acc[nt] = (f32x4){0.f, 0.f, 0.f, 0.f};
      int oc = (npair * 2 + nt) * 16 + lm;
      #pragma unroll
      for (int ks = 0; ks < 2; ks++) {
        int gg = ks * 4 + quad;
        bf16x8 bfrag = *(const bf16x8*)&pwb[oc * 64 + ((gg ^ (oc & 7)) << 3)];
        acc[nt] = __builtin_amdgcn_mfma_f32_16x16x32_bf16(afrag[ks], bfrag, acc[nt], 0, 0, 0);
      }
    }

    // BN + bf16 slot store
    unsigned short* slotp = wsb + (size_t)nd.slot * NODE_ELEMS;
    #pragma unroll
    for (int nt = 0; nt < 2; nt++) {
      int oc = (npair * 2 + nt) * 16 + lm;
      int gi = node * 64 + oc;
      float inv = gmall[gi] / sqrtf(vrall[gi] + 1e-5f);
      float mn = mnall[gi], btv = btall[gi];
      #pragma unroll
      for (int rr = 0; rr < 4; rr++) {
        int pos = mtile * 16 + quad * 4 + rr;
        int gy = ty + (pos >> 3), gx = tx + (pos & 7);
        size_t base = (((size_t)(b * 56 + gy)) * 56 + gx) * 64 + oc;
        slotp[base] = f2bf((acc[nt][rr] - mn) * inv + btv);
      }
    }
  }
}

// Levels >= 1: node-parallel, one (node, tile) per block. All nodes here have
// npred >= 1 (npred==0 <=> level 0), so the input branch is gone.
__global__ __launch_bounds__(256) void level_kernel(
    GroupArg g,
    const float* __restrict__ dwall,
    const float* __restrict__ pwall,
    const float* __restrict__ gmall,
    const float* __restrict__ btall,
    const float* __restrict__ mnall,
    const float* __restrict__ vrall,
    const float* __restrict__ aggw,
    unsigned short* __restrict__ wsb)   // bf16 slots
{
  __shared__ float smem[3840];                          // halo [6r][10c][64ch] fp32
  __shared__ __align__(16) unsigned short pwb[4096];    // pw weights (bf16, swz)
  __shared__ __align__(16) unsigned short tbuf[2048];   // t[32 pos][64 c] (bf16, swz)
  __shared__ float wlds[32];                            // agg weights

  const int bid = blockIdx.x;
  const int nid = bid / 784;          // node index within this level
  const int r   = bid - nid * 784;
  const int b = r & 7;                // image == XCD
  const int m = r >> 3;               // tile [0,98)
  const int t = threadIdx.x;
  const int ty = (m / 7) * 4;         // 14 y-tiles of 4 rows
  const int tx = (m % 7) * 8;         // 7 x-tiles of 8 cols

  const NodeDesc nd = g.d[nid];
  const int node = nd.node;

  const int dwc = t & 63;
  const int pbase = (t >> 6) * 8;

  const float* k9 = dwall + (node * 64 + dwc) * 9;
  float kk9[9];
  #pragma unroll
  for (int q = 0; q < 9; q++) kk9[q] = k9[q];

  float tv[8];

  // aggregate + relu into fp32 NHWC halo (480 units of 8 ch = 16 B)
  if (t < nd.npred) {
    float wv = 1.f / (1.f + expf(-aggw[node * 32 + t]));
    wlds[t] = (nd.npred == 1) ? 1.0f : wv;
  }
  const int np = nd.npred;
  float sa[2][8];
  int off[2];
  bool inb[2];
  #pragma unroll
  for (int u = 0; u < 2; u++) {
    int idx = t + u * 256;
    bool valid = (u == 0) || (t < 224);
    int pos = idx >> 3, q8 = idx & 7;
    int hy = pos / 10, hx = pos - hy * 10;
    int gy = ty + hy - 1, gx = tx + hx - 1;
    inb[u] = valid && ((unsigned)gy < 56u) && ((unsigned)gx < 56u);
    off[u] = ((b * 56 + gy) * 56 + gx) * 64 + q8 * 8;
    #pragma unroll
    for (int q = 0; q < 8; q++) sa[u][q] = 0.f;
  }
  __syncthreads();   // B1: wlds visible
  for (int p0 = 0; p0 < np; p0 += 4) {
    uint4 v[4][2];
    #pragma unroll
    for (int pp = 0; pp < 4; pp++) {
      if (p0 + pp < np) {
        const unsigned short* pb = wsb + (size_t)nd.pred_slot[p0 + pp] * NODE_ELEMS;
        #pragma unroll
        for (int u = 0; u < 2; u++)
          if (inb[u]) v[pp][u] = *(const uint4*)(pb + off[u]);
      }
    }
    #pragma unroll
    for (int pp = 0; pp < 4; pp++) {
      if (p0 + pp < np) {
        float wv = wlds[p0 + pp];
        #pragma unroll
        for (int u = 0; u < 2; u++) {
          if (inb[u]) {
            sa[u][0] = fmaf(wv, bf2f_lo(v[pp][u].x), sa[u][0]);
            sa[u][1] = fmaf(wv, bf2f_hi(v[pp][u].x), sa[u][1]);
            sa[u][2] = fmaf(wv, bf2f_lo(v[pp][u].y), sa[u][2]);
            sa[u][3] = fmaf(wv, bf2f_hi(v[pp][u].y), sa[u][3]);
            sa[u][4] = fmaf(wv, bf2f_lo(v[pp][u].z), sa[u][4]);
            sa[u][5] = fmaf(wv, bf2f_hi(v[pp][u].z), sa[u][5]);
            sa[u][6] = fmaf(wv, bf2f_lo(v[pp][u].w), sa[u][6]);
            sa[u][7] = fmaf(wv, bf2f_hi(v[pp][u].w), sa[u][7]);
          }
        }
      }
    }
  }
  #pragma unroll
  for (int u = 0; u < 2; u++) {
    int idx = t + u * 256;
    if ((u == 0) || (t < 224)) {
      float4 s0 = make_float4(fmaxf(sa[u][0], 0.f), fmaxf(sa[u][1], 0.f),
                              fmaxf(sa[u][2], 0.f), fmaxf(sa[u][3], 0.f));
      float4 s1 = make_float4(fmaxf(sa[u][4], 0.f), fmaxf(sa[u][5], 0.f),
                              fmaxf(sa[u][6], 0.f), fmaxf(sa[u][7], 0.f));
      *(float4*)&smem[idx * 8] = s0;
      *(float4*)&smem[idx * 8 + 4] = s1;
    }
  }
  // stage pw (overlaps the B2 wait; consumed after B3)
  {
    const float* pwn = pwall + node * 4096;
    #pragma unroll
    for (int i = 0; i < 16; i++) {
      int gidx = t + 256 * i;
      int o = gidx >> 6, cc = gidx & 63;
      pwb[o * 64 + ((((cc >> 3) ^ (o & 7)) << 3) | (cc & 7))] = f2bf(pwn[gidx]);
    }
  }
  __syncthreads();   // B2: halo ready
  #pragma unroll
  for (int jj = 0; jj < 8; jj++) {
    int p = pbase + jj;
    int py = p >> 3, px = p & 7;
    const float* r0 = smem + (py * 10 + px) * 64 + dwc;
    tv[jj] = r0[0]    * kk9[0] + r0[64]   * kk9[1] + r0[128]  * kk9[2]
           + r0[640]  * kk9[3] + r0[704]  * kk9[4] + r0[768]  * kk9[5]
           + r0[1280] * kk9[6] + r0[1344] * kk9[7] + r0[1408] * kk9[8];
  }

  // t matrix bf16, granule-swizzled: (p,c) -> p*64 + (((c>>3)^(p&7))<<3)|(c&7)
  #pragma unroll
  for (int jj = 0; jj < 8; jj++) {
    int p = pbase + jj;
    tbuf[p * 64 + ((((dwc >> 3) ^ (p & 7)) << 3) | (dwc & 7))] = f2bf(tv[jj]);
  }
  __syncthreads();   // B3: tbuf + pwb ready

  // MFMA pointwise: D[32 pos][64 oc] = t x pw^T
  const int lane = t & 63;
  const int wave = t >> 6;
  const int mtile = wave & 1;
  const int npair = wave >> 1;
  const int lm = lane & 15;
  const int quad = lane >> 4;

  bf16x8 afrag[2];
  #pragma unroll
  for (int ks = 0; ks < 2; ks++) {
    int pos = mtile * 16 + lm;
    int gg = ks * 4 + quad;
    afrag[ks] = *(const bf16x8*)&tbuf[pos * 64 + ((gg ^ (pos & 7)) << 3)];
  }
  f32x4 acc[2];
  #pragma unroll
  for (int nt = 0; nt < 2; nt++) {
    acc[nt] = (f32x4){0.f, 0.f, 0.f, 0.f};
    int oc = (npair * 2 + nt) * 16 + lm;
    #pragma unroll
    for (int ks = 0; ks < 2; ks++) {
      int gg = ks * 4 + quad;
      bf16x8 bfrag = *(const bf16x8*)&pwb[oc * 64 + ((gg ^ (oc & 7)) << 3)];
      acc[nt] = __builtin_amdgcn_mfma_f32_16x16x32_bf16(afrag[ks], bfrag, acc[nt], 0, 0, 0);
    }
  }

  // BN + bf16 slot store. D: col=lane&15 (oc), row=quad*4+reg (pos in tile)
  unsigned short* slotp = wsb + (size_t)nd.slot * NODE_ELEMS;
  #pragma unroll
  for (int nt = 0; nt < 2; nt++) {
    int oc = (npair * 2 + nt) * 16 + lm;
    int gi = node * 64 + oc;
    float inv = gmall[gi] / sqrtf(vrall[gi] + 1e-5f);
    float mn = mnall[gi], btv = btall[gi];
    #pragma unroll
    for (int rr = 0; rr < 4; rr++) {
      int pos = mtile * 16 + quad * 4 + rr;
      int gy = ty + (pos >> 3), gx = tx + (pos & 7);
      size_t base = (((size_t)(b * 56 + gy)) * 56 + gx) * 64 + oc;
      slotp[base] = f2bf((acc[nt][rr] - mn) * inv + btv);
    }
  }
}

// Mean of FINAL bf16 slots (fp32 accumulate) -> NCHW d_out.
// Block per (b, y, half-x): 8*56*2 = 896 blocks. uint4 loads (8 bf16),
// slot loop batched 4-wide into named regs -> 4 loads in flight.
__global__ __launch_bounds__(256) void finalize_kernel(
    FinalArg fa, const unsigned short* __restrict__ wsb,
    float* __restrict__ out, float inv_nf)
{
  __shared__ float lds[64 * 29];      // [c][x-half] transpose buffer, pad 29
  const int bid = blockIdx.x;
  const int half = bid & 1;
  const int by = bid >> 1;
  const int b = by / 56, y = by - b * 56;
  const int x0 = half * 28;
  const size_t rbase = ((((size_t)b * 56 + y) * 56) + x0) * 64;  // [x][c] bf16
  const int t = threadIdx.x;
  const int nf = fa.nf;

  if (t < 224) {                      // 28 x * 8 channel-groups of 8
    const int xx = t >> 3, q8 = t & 7;
    const unsigned short* p0 = wsb + rbase + xx * 64 + q8 * 8;
    float s0 = 0.f, s1 = 0.f, s2 = 0.f, s3 = 0.f,
          s4 = 0.f, s5 = 0.f, s6 = 0.f, s7 = 0.f;
    for (int f0 = 0; f0 < nf; f0 += 4) {
      uint4 va, vb, vc, vd;
      if (f0 + 0 < nf) va = *(const uint4*)(p0 + (size_t)fa.slot[f0 + 0] * NODE_ELEMS);
      if (f0 + 1 < nf) vb = *(const uint4*)(p0 + (size_t)fa.slot[f0 + 1] * NODE_ELEMS);
      if (f0 + 2 < nf) vc = *(const uint4*)(p0 + (size_t)fa.slot[f0 + 2] * NODE_ELEMS);
      if (f0 + 3 < nf) vd = *(const uint4*)(p0 + (size_t)fa.slot[f0 + 3] * NODE_ELEMS);
      if (f0 + 0 < nf) {
        s0 += bf2f_lo(va.x); s1 += bf2f_hi(va.x); s2 += bf2f_lo(va.y); s3 += bf2f_hi(va.y);
        s4 += bf2f_lo(va.z); s5 += bf2f_hi(va.z); s6 += bf2f_lo(va.w); s7 += bf2f_hi(va.w);
      }
      if (f0 + 1 < nf) {
        s0 += bf2f_lo(vb.x); s1 += bf2f_hi(vb.x); s2 += bf2f_lo(vb.y); s3 += bf2f_hi(vb.y);
        s4 += bf2f_lo(vb.z); s5 += bf2f_hi(vb.z); s6 += bf2f_lo(vb.w); s7 += bf2f_hi(vb.w);
      }
      if (f0 + 2 < nf) {
        s0 += bf2f_lo(vc.x); s1 += bf2f_hi(vc.x); s2 += bf2f_lo(vc.y); s3 += bf2f_hi(vc.y);
        s4 += bf2f_lo(vc.z); s5 += bf2f_hi(vc.z); s6 += bf2f_lo(vc.w); s7 += bf2f_hi(vc.w);
      }
      if (f0 + 3 < nf) {
        s0 += bf2f_lo(vd.x); s1 += bf2f_hi(vd.x); s2 += bf2f_lo(vd.y); s3 += bf2f_hi(vd.y);
        s4 += bf2f_lo(vd.z); s5 += bf2f_hi(vd.z); s6 += bf2f_lo(vd.w); s7 += bf2f_hi(vd.w);
      }
    }
    float* dl = lds + (q8 * 8) * 29 + xx;
    dl[0 * 29] = s0 * inv_nf; dl[1 * 29] = s1 * inv_nf;
    dl[2 * 29] = s2 * inv_nf; dl[3 * 29] = s3 * inv_nf;
    dl[4 * 29] = s4 * inv_nf; dl[5 * 29] = s5 * inv_nf;
    dl[6 * 29] = s6 * inv_nf; dl[7 * 29] = s7 * inv_nf;
  }
  __syncthreads();
  float* dst = out + (size_t)b * 64 * 3136 + (size_t)y * 56 + x0;
  for (int j = t; j < 1792; j += 256) {     // 64 c * 28 x
    int c = j / 28, xx = j - c * 28;
    dst[(size_t)c * 3136 + xx] = lds[c * 29 + xx];
  }
}

// ---------------- launcher ----------------
extern "C" void kernel_launch(void* const* d_in, const int* in_sizes, int n_in,
                              void* d_out, int out_size, void* d_ws, size_t ws_size,
                              hipStream_t stream) {
  (void)in_sizes; (void)n_in; (void)ws_size; (void)out_size;
  const float* x     = (const float*)d_in[0];
  const float* dw    = (const float*)d_in[1];
  const float* pw    = (const float*)d_in[2];
  const float* gamma = (const float*)d_in[3];
  const float* beta  = (const float*)d_in[4];
  const float* mean  = (const float*)d_in[5];
  const float* var   = (const float*)d_in[6];
  const float* aggw  = (const float*)d_in[7];
  unsigned short* wsb = (unsigned short*)d_ws;
  float* out = (float*)d_out;

  bool adj[NN][NN];
  compute_adj(adj);

  int npred[NN], preds[NN][NN], nsucc[NN], ispan[NN], level[NN];
  for (int j = 0; j < NN; j++) {
    npred[j] = 0;
    for (int i = 0; i < j; i++) if (adj[i][j]) preds[j][npred[j]++] = i;
  }
  for (int i = 0; i < NN; i++) {
    nsucc[i] = 0; ispan[i] = NN;
    int mx = -1;
    for (int j = i + 1; j < NN; j++) if (adj[i][j]) { nsucc[i]++; mx = j; }
    if (nsucc[i] > 0) ispan[i] = mx;
  }
  int maxlev = 0;
  for (int j = 0; j < NN; j++) {
    int lv = 0;
    for (int p = 0; p < npred[j]; p++) {
      int cand = level[preds[j][p]] + 1;
      if (cand > lv) lv = cand;
    }
    level[j] = lv;
    if (lv > maxlev) maxlev = lv;
  }
  bool isfinal[NN]; int nf = 0;
  for (int i = 0; i < NN; i++) { isfinal[i] = (ispan[i] >= NN - 1); if (isfinal[i]) nf++; }
  int lastlvl[NN];
  for (int i = 0; i < NN; i++) {
    lastlvl[i] = -1;
    for (int j = i + 1; j < NN; j++) if (adj[i][j] && level[j] > lastlvl[i]) lastlvl[i] = level[j];
  }
  // slot allocation: every node gets a slot; FINAL slots never freed.
  int slot[NN]; bool used[NN];
  for (int s = 0; s < NN; s++) used[s] = false;
  for (int L = 0; L <= maxlev; L++) {
    for (int i = 0; i < NN; i++) {
      if (level[i] != L) continue;
      int s = 0; while (used[s]) s++;
      used[s] = true; slot[i] = s;
    }
    for (int i = 0; i < NN; i++)
      if (level[i] <= L && !isfinal[i] && lastlvl[i] == L)
        used[slot[i]] = false;
  }

  float inv_nf = 1.0f / (float)nf;

  for (int L = 0; L <= maxlev; L++) {
    GroupArg g; g.n = 0;
    for (int i = 0; i < NN; i++) {
      if (level[i] != L) continue;
      NodeDesc& nd = g.d[g.n++];
      nd.node = (uint8_t)i;
      nd.npred = (uint8_t)npred[i];
      nd.slot = (uint8_t)slot[i];
      nd.flags = 0;
      for (int p = 0; p < npred[i]; p++) nd.pred_slot[p] = (uint8_t)slot[preds[i][p]];
    }
    if (g.n > 0) {
      if (L == 0) {
        input_kernel<<<784, 256, 0, stream>>>(g, x, dw, pw, gamma, beta,
                                              mean, var, wsb);
      } else {
        level_kernel<<<784 * g.n, 256, 0, stream>>>(g, dw, pw, gamma, beta,
                                                    mean, var, aggw, wsb);
      }
    }
  }

  FinalArg fa; fa.nf = 0;
  for (int i = 0; i < NN; i++) if (isfinal[i]) fa.slot[fa.nf++] = (uint8_t)slot[i];
  finalize_kernel<<<896, 256, 0, stream>>>(fa, wsb, out, inv_nf);
}